// Round 6
// baseline (71.385 us; speedup 1.0000x reference)
//
#include <hip/hip_runtime.h>
#include <hip/hip_cooperative_groups.h>
#include <math.h>

namespace cg = cooperative_groups;

#define BSZ 512
#define DSZ 512
#define MARGIN 0.4f
#define ALPHA 1.0f
#define NBLK 256   // 16x16 grid, one 32x32 dist tile each; 2 anchors each in phase 2

// One cooperative kernel:
//   phase 1: dist tile (fused norms + Gram), per-wave private LDS slabs
//   grid.sync()
//   phase 2: ranked-list counting, 2 anchors per block
//   last-arriving block: final 256-partial reduce -> out[0]
__global__ __launch_bounds__(256) void rll_fused(const float* __restrict__ emb,
                                                 const int* __restrict__ labels,
                                                 float* __restrict__ dist,
                                                 float* __restrict__ partial,
                                                 int* __restrict__ counter,
                                                 float* __restrict__ out) {
    // ---------------- shared memory ----------------
    __shared__ float As[4][32][32];    // phase 1: [wave][k][m]
    __shared__ float Bs[4][32][32];
    __shared__ float comb[4][64][16];  // accumulator combine
    __shared__ float sAq[4][2][32];    // per-wave per-khalf row sumsq
    __shared__ float sBq[4][2][32];
    __shared__ float invA[32];
    __shared__ float invB[32];
    __shared__ float dsh[2][BSZ];      // phase 2
    __shared__ int   lsh[BSZ];
    __shared__ int   pos[2][BSZ];
    __shared__ int   npos[2];
    __shared__ float wsum[2][2];
    __shared__ bool  last;

    const int tid = threadIdx.x;
    const int bid = blockIdx.y * 16 + blockIdx.x;   // 0..255
    if (bid == 0 && tid == 0) counter[0] = 0;       // re-arm for this replay

    // ================= phase 1: dist tile =================
    {
        const int w = tid >> 6;          // wave 0..3
        const int l = tid & 63;
        const int brow = blockIdx.y * 32;
        const int bcol = blockIdx.x * 32;
        const int sm = l & 31;
        const int shalf = l >> 5;
        const int sk0 = shalf * 16;
        const int ty = l >> 3;
        const int tx = l & 7;

        float acc[4][4];
        #pragma unroll
        for (int i = 0; i < 4; ++i)
            #pragma unroll
            for (int j = 0; j < 4; ++j) acc[i][j] = 0.f;
        float ssa = 0.f, ssb = 0.f;

        #pragma unroll
        for (int r = 0; r < 4; ++r) {
            const int kt = w * 128 + r * 32;
            const float4* pa = (const float4*)(emb + (size_t)(brow + sm) * DSZ + kt + sk0);
            const float4* pb = (const float4*)(emb + (size_t)(bcol + sm) * DSZ + kt + sk0);
            float va[16], vb[16];
            *(float4*)&va[0]  = pa[0];
            *(float4*)&va[4]  = pa[1];
            *(float4*)&va[8]  = pa[2];
            *(float4*)&va[12] = pa[3];
            *(float4*)&vb[0]  = pb[0];
            *(float4*)&vb[4]  = pb[1];
            *(float4*)&vb[8]  = pb[2];
            *(float4*)&vb[12] = pb[3];
            #pragma unroll
            for (int q = 0; q < 16; ++q) {
                As[w][sk0 + q][sm] = va[q];
                Bs[w][sk0 + q][sm] = vb[q];
                ssa += va[q] * va[q];
                ssb += vb[q] * vb[q];
            }
            // per-wave private slab: same-wave write->read ordered by lgkmcnt
            #pragma unroll
            for (int k = 0; k < 32; ++k) {
                const float4 av = *(const float4*)&As[w][k][ty << 2];
                const float4 bv = *(const float4*)&Bs[w][k][tx << 2];
                float a_[4] = {av.x, av.y, av.z, av.w};
                float b_[4] = {bv.x, bv.y, bv.z, bv.w};
                #pragma unroll
                for (int i = 0; i < 4; ++i)
                    #pragma unroll
                    for (int j = 0; j < 4; ++j)
                        acc[i][j] += a_[i] * b_[j];
            }
        }

        sAq[w][shalf][sm] = ssa;
        sBq[w][shalf][sm] = ssb;
        #pragma unroll
        for (int i = 0; i < 4; ++i)
            *(float4*)&comb[w][l][i * 4] =
                make_float4(acc[i][0], acc[i][1], acc[i][2], acc[i][3]);
        __syncthreads();

        // inv norms into a tiny table (threads 0..63)
        if (tid < 64) {
            const int m = tid & 31;
            float s = 0.f;
            if (tid < 32) {
                #pragma unroll
                for (int ww = 0; ww < 4; ++ww) s += sAq[ww][0][m] + sAq[ww][1][m];
                invA[m] = 1.0f / fmaxf(sqrtf(s), 1e-12f);
            } else {
                #pragma unroll
                for (int ww = 0; ww < 4; ++ww) s += sBq[ww][0][m] + sBq[ww][1][m];
                invB[m] = 1.0f / fmaxf(sqrtf(s), 1e-12f);
            }
        }
        __syncthreads();

        // parallel epilogue: each of 256 threads produces 4 outputs
        {
            const int o = tid << 2;               // 0..1020
            const int i_local = o >> 5;           // 0..31
            const int txq = (o & 31) >> 2;        // 0..7
            const int lane2 = ((i_local >> 2) << 3) + txq;
            const int ii = (i_local & 3) << 2;
            const float4 c0 = *(const float4*)&comb[0][lane2][ii];
            const float4 c1 = *(const float4*)&comb[1][lane2][ii];
            const float4 c2 = *(const float4*)&comb[2][lane2][ii];
            const float4 c3 = *(const float4*)&comb[3][lane2][ii];
            const float ia = invA[i_local];
            const float ib0 = invB[txq * 4 + 0];
            const float ib1 = invB[txq * 4 + 1];
            const float ib2 = invB[txq * 4 + 2];
            const float ib3 = invB[txq * 4 + 3];
            float4 oo;
            oo.x = sqrtf(fmaxf(2.0f - 2.0f * (c0.x + c1.x + c2.x + c3.x) * ia * ib0, 0.0f));
            oo.y = sqrtf(fmaxf(2.0f - 2.0f * (c0.y + c1.y + c2.y + c3.y) * ia * ib1, 0.0f));
            oo.z = sqrtf(fmaxf(2.0f - 2.0f * (c0.z + c1.z + c2.z + c3.z) * ia * ib2, 0.0f));
            oo.w = sqrtf(fmaxf(2.0f - 2.0f * (c0.w + c1.w + c2.w + c3.w) * ia * ib3, 0.0f));
            *(float4*)&dist[(size_t)(brow + i_local) * BSZ + bcol + txq * 4] = oo;
        }
    }

    // ================= grid-wide barrier =================
    cg::this_grid().sync();

    // ================= phase 2: counting (2 anchors/block) =================
    {
        const int s    = tid >> 7;            // anchor slot 0/1
        const int tid2 = tid & 127;
        const int i    = bid * 2 + s;         // anchor index

        *(float4*)&dsh[s][tid2 * 4] = ((const float4*)(dist + (size_t)i * BSZ))[tid2];
        if (s == 0) *(int4*)&lsh[tid2 * 4] = ((const int4*)labels)[tid2];
        if (tid2 == 0) npos[s] = 0;
        if (tid < 4) wsum[tid >> 1][tid & 1] = 0.f;
        __syncthreads();

        const int li = lsh[i];
        #pragma unroll
        for (int q = 0; q < 4; ++q) {
            const int j = tid2 + q * 128;
            if (j != i && lsh[j] == li) {
                const int idx = atomicAdd(&npos[s], 1);
                pos[s][idx] = j;
            }
        }
        __syncthreads();

        const int w2   = (tid >> 6) & 1;      // wave within slot
        const int lane = tid & 63;
        const int np = npos[s];
        float acc = 0.f;
        for (int p = w2; p < np; p += 2) {
            const int j = pos[s][p];
            const float thr = dsh[s][j] + MARGIN;
            int cnt = 0;
            #pragma unroll
            for (int kk = 0; kk < BSZ / 64; ++kk) {
                const int k = lane + kk * 64;
                cnt += (lsh[k] != li && dsh[s][k] < thr) ? 1 : 0;
            }
            #pragma unroll
            for (int off = 32; off > 0; off >>= 1) cnt += __shfl_down(cnt, off);
            if (lane == 0 && cnt > 0) acc += log1pf((float)cnt);
        }
        if (lane == 0) wsum[s][w2] = acc;
        __syncthreads();

        if (tid == 0) {
            partial[bid] = wsum[0][0] + wsum[0][1] + wsum[1][0] + wsum[1][1];
            __threadfence();
            const int old = atomicAdd(counter, 1);
            last = (old == NBLK - 1);
        }
        __syncthreads();

        if (last) {
            __threadfence();
            if (tid < 64) {
                volatile const float* vp = (volatile const float*)partial;
                float t = 0.f;
                #pragma unroll
                for (int q = 0; q < NBLK / 64; ++q) t += vp[tid + q * 64];
                #pragma unroll
                for (int off = 32; off > 0; off >>= 1) t += __shfl_down(t, off);
                if (tid == 0) out[0] = t * (ALPHA / (512.0f + 1e-8f));
            }
        }
    }
}

extern "C" void kernel_launch(void* const* d_in, const int* in_sizes, int n_in,
                              void* d_out, int out_size, void* d_ws, size_t ws_size,
                              hipStream_t stream) {
    const float* emb    = (const float*)d_in[0];
    const int*   labels = (const int*)d_in[1];
    float* out = (float*)d_out;

    // workspace: dist (512*512 f32) | partial (256 f32) | counter (int)
    float* dist    = (float*)d_ws;
    float* partial = dist + (size_t)BSZ * BSZ;
    int*   counter = (int*)(partial + NBLK);

    void* args[] = {(void*)&emb, (void*)&labels, (void*)&dist,
                    (void*)&partial, (void*)&counter, (void*)&out};
    hipLaunchCooperativeKernel((const void*)rll_fused, dim3(16, 16), dim3(256),
                               args, 0, stream);
}

// Round 7
// 28.434 us; speedup vs baseline: 2.5105x; 2.5105x over previous
//
#include <hip/hip_runtime.h>
#include <math.h>

#define BSZ 512
#define DSZ 512
#define MARGIN 0.4f
#define ALPHA 1.0f

typedef __attribute__((ext_vector_type(8))) short bf16x8;
typedef __attribute__((ext_vector_type(4))) float f32x4;

static __device__ __forceinline__ unsigned short f2bf(float f) {
    // round-to-nearest-even bf16 via f32 bit trick
    unsigned int u = __float_as_uint(f);
    unsigned int r = (u + 0x7fff + ((u >> 16) & 1)) >> 16;
    return (unsigned short)r;
}

// ---------------- Kernel 1: bf16-MFMA Gram + fused norms + dist -------
// 256 blocks (one 32x32 tile), 256 threads = 4 waves; wave w owns
// k-quarter [128w, 128w+128) in its own private LDS slab (no main-loop
// barriers). dist = sqrt(max(2 - 2*dot*inv_i*inv_j, 0)).
__global__ __launch_bounds__(256) void rll_dist(const float* __restrict__ emb,
                                                float* __restrict__ dist,
                                                int* __restrict__ counter) {
    __shared__ unsigned short Abf[4][32][136];  // [wave][row][128k + 8 pad]
    __shared__ unsigned short Bbf[4][32][136];
    __shared__ float sAq[4][32];                // per-wave row sumsq (f32, exact)
    __shared__ float sBq[4][32];
    __shared__ float invA[32];
    __shared__ float invB[32];
    __shared__ float comb[4][64][16];           // k-quarter partial C combine

    const int tid = threadIdx.x;
    const int w = tid >> 6;                     // wave 0..3
    const int l = tid & 63;
    if (blockIdx.x == 0 && blockIdx.y == 0 && tid == 0) counter[0] = 0;
    const int brow = blockIdx.y * 32;
    const int bcol = blockIdx.x * 32;

    // ---- staging: f32 -> bf16 into this wave's slab; exact f32 sumsq ----
    const int srow = l >> 1;                    // 0..31
    const int sh = l & 1;                       // k-half of the quarter
    const int kbase = w * 128 + sh * 64;
    {
        const float4* src = (const float4*)(emb + (size_t)(brow + srow) * DSZ + kbase);
        float4 v[16];
        #pragma unroll
        for (int c = 0; c < 16; ++c) v[c] = src[c];
        float ss = 0.f;
        #pragma unroll
        for (int c = 0; c < 16; ++c)
            ss += v[c].x * v[c].x + v[c].y * v[c].y + v[c].z * v[c].z + v[c].w * v[c].w;
        unsigned short* drow = &Abf[w][srow][sh * 64];
        #pragma unroll
        for (int c = 0; c < 8; ++c) {
            const float4 p = v[2 * c], q = v[2 * c + 1];
            union { unsigned short u[8]; uint4 vv; } pk;
            pk.u[0] = f2bf(p.x); pk.u[1] = f2bf(p.y);
            pk.u[2] = f2bf(p.z); pk.u[3] = f2bf(p.w);
            pk.u[4] = f2bf(q.x); pk.u[5] = f2bf(q.y);
            pk.u[6] = f2bf(q.z); pk.u[7] = f2bf(q.w);
            *(uint4*)&drow[c * 8] = pk.vv;
        }
        ss += __shfl_xor(ss, 1);
        if (sh == 0) sAq[w][srow] = ss;
    }
    {
        const float4* src = (const float4*)(emb + (size_t)(bcol + srow) * DSZ + kbase);
        float4 v[16];
        #pragma unroll
        for (int c = 0; c < 16; ++c) v[c] = src[c];
        float ss = 0.f;
        #pragma unroll
        for (int c = 0; c < 16; ++c)
            ss += v[c].x * v[c].x + v[c].y * v[c].y + v[c].z * v[c].z + v[c].w * v[c].w;
        unsigned short* drow = &Bbf[w][srow][sh * 64];
        #pragma unroll
        for (int c = 0; c < 8; ++c) {
            const float4 p = v[2 * c], q = v[2 * c + 1];
            union { unsigned short u[8]; uint4 vv; } pk;
            pk.u[0] = f2bf(p.x); pk.u[1] = f2bf(p.y);
            pk.u[2] = f2bf(p.z); pk.u[3] = f2bf(p.w);
            pk.u[4] = f2bf(q.x); pk.u[5] = f2bf(q.y);
            pk.u[6] = f2bf(q.z); pk.u[7] = f2bf(q.w);
            *(uint4*)&drow[c * 8] = pk.vv;
        }
        ss += __shfl_xor(ss, 1);
        if (sh == 0) sBq[w][srow] = ss;
    }
    // wave reads only its own slab below: same-wave lgkmcnt ordering, no barrier.

    // ---- MFMA: 2x2 tiles of 16x16x32 over this wave's k-quarter ----
    f32x4 acc00 = {0.f, 0.f, 0.f, 0.f}, acc01 = {0.f, 0.f, 0.f, 0.f};
    f32x4 acc10 = {0.f, 0.f, 0.f, 0.f}, acc11 = {0.f, 0.f, 0.f, 0.f};
    const int fr = l & 15;                      // fragment row/col
    const int fk = (l >> 4) * 8;                // fragment k-slice
    #pragma unroll
    for (int kc = 0; kc < 4; ++kc) {
        const int ko = kc * 32 + fk;
        const bf16x8 a0 = *(const bf16x8*)&Abf[w][fr][ko];
        const bf16x8 a1 = *(const bf16x8*)&Abf[w][16 + fr][ko];
        const bf16x8 b0 = *(const bf16x8*)&Bbf[w][fr][ko];
        const bf16x8 b1 = *(const bf16x8*)&Bbf[w][16 + fr][ko];
        acc00 = __builtin_amdgcn_mfma_f32_16x16x32_bf16(a0, b0, acc00, 0, 0, 0);
        acc01 = __builtin_amdgcn_mfma_f32_16x16x32_bf16(a0, b1, acc01, 0, 0, 0);
        acc10 = __builtin_amdgcn_mfma_f32_16x16x32_bf16(a1, b0, acc10, 0, 0, 0);
        acc11 = __builtin_amdgcn_mfma_f32_16x16x32_bf16(a1, b1, acc11, 0, 0, 0);
    }
    *(f32x4*)&comb[w][l][0]  = acc00;
    *(f32x4*)&comb[w][l][4]  = acc01;
    *(f32x4*)&comb[w][l][8]  = acc10;
    *(f32x4*)&comb[w][l][12] = acc11;
    __syncthreads();

    // ---- inverse norms (exact f32) ----
    if (tid < 32) {
        const float s = sAq[0][tid] + sAq[1][tid] + sAq[2][tid] + sAq[3][tid];
        invA[tid] = 1.0f / fmaxf(sqrtf(s), 1e-12f);
    } else if (tid < 64) {
        const int m = tid - 32;
        const float s = sBq[0][m] + sBq[1][m] + sBq[2][m] + sBq[3][m];
        invB[m] = 1.0f / fmaxf(sqrtf(s), 1e-12f);
    }
    __syncthreads();

    // ---- epilogue: sum k-quarters, normalize, dist ----
    // D mapping (m89): col = lane&15, row = (lane>>4)*4 + reg, per 16x16 tile.
    {
        const int el = tid & 63;
        const int eq = tid >> 6;                // which (tr,tc) quadrant
        const int tr = eq >> 1, tc = eq & 1;
        const f32x4 c0 = *(const f32x4*)&comb[0][el][eq * 4];
        const f32x4 c1 = *(const f32x4*)&comb[1][el][eq * 4];
        const f32x4 c2 = *(const f32x4*)&comb[2][el][eq * 4];
        const f32x4 c3 = *(const f32x4*)&comb[3][el][eq * 4];
        const f32x4 s = c0 + c1 + c2 + c3;
        const int colo = tc * 16 + (el & 15);
        const int rowbase = tr * 16 + ((el >> 4) << 2);
        const float ib = invB[colo];
        #pragma unroll
        for (int r = 0; r < 4; ++r) {
            const int row = rowbase + r;
            const float d = sqrtf(fmaxf(2.0f - 2.0f * s[r] * invA[row] * ib, 0.0f));
            dist[(size_t)(brow + row) * BSZ + bcol + colo] = d;
        }
    }
}

// ------- Kernel 2: ranked-list counting + last-block final reduce -----
// grid = 512 blocks (one per anchor i), block = 256 threads (4 waves).
__global__ void rll_count(const float* __restrict__ dist,
                          const int* __restrict__ labels,
                          float* __restrict__ partial,
                          int* __restrict__ counter,
                          float* __restrict__ out) {
    __shared__ float dsh[BSZ];
    __shared__ int   lsh[BSZ];
    __shared__ int   pos[BSZ];
    __shared__ int   npos;
    __shared__ float wsum[4];
    __shared__ bool  last;
    const int i = blockIdx.x;
    const int tid = threadIdx.x;
    if (tid == 0) npos = 0;
    if (tid < 128) {
        const float4 d4 = ((const float4*)(dist + (size_t)i * BSZ))[tid];
        *(float4*)&dsh[tid * 4] = d4;
        const int4 l4 = ((const int4*)labels)[tid];
        *(int4*)&lsh[tid * 4] = l4;
    }
    __syncthreads();
    const int li = lsh[i];
    for (int j = tid; j < BSZ; j += 256) {
        if (j != i && lsh[j] == li) {
            int idx = atomicAdd(&npos, 1);
            pos[idx] = j;
        }
    }
    if (tid < 4) wsum[tid] = 0.f;
    __syncthreads();
    const int wave = tid >> 6, lane = tid & 63;
    const int np = npos;
    float acc = 0.f;
    for (int p = wave; p < np; p += 4) {
        const int j = pos[p];
        const float thr = dsh[j] + MARGIN;
        int cnt = 0;
        #pragma unroll
        for (int kk = 0; kk < BSZ / 64; ++kk) {
            const int k = lane + kk * 64;
            cnt += (lsh[k] != li && dsh[k] < thr) ? 1 : 0;
        }
        #pragma unroll
        for (int off = 32; off > 0; off >>= 1) cnt += __shfl_down(cnt, off);
        if (lane == 0 && cnt > 0) acc += log1pf((float)cnt);
    }
    if (lane == 0) wsum[wave] = acc;
    __syncthreads();
    if (tid == 0) {
        partial[i] = wsum[0] + wsum[1] + wsum[2] + wsum[3];
        __threadfence();
        const int old = atomicAdd(counter, 1);
        last = (old == BSZ - 1);
    }
    __syncthreads();
    if (last) {
        __threadfence();
        if (tid < 64) {
            volatile const float* vp = (volatile const float*)partial;
            float s = 0.f;
            #pragma unroll
            for (int q = 0; q < BSZ / 64; ++q) s += vp[tid + q * 64];
            #pragma unroll
            for (int off = 32; off > 0; off >>= 1) s += __shfl_down(s, off);
            if (tid == 0) out[0] = s * (ALPHA / (512.0f + 1e-8f));
        }
    }
}

extern "C" void kernel_launch(void* const* d_in, const int* in_sizes, int n_in,
                              void* d_out, int out_size, void* d_ws, size_t ws_size,
                              hipStream_t stream) {
    const float* emb    = (const float*)d_in[0];
    const int*   labels = (const int*)d_in[1];
    float* out = (float*)d_out;

    // workspace: dist (512*512 f32) | partial (512 f32) | counter (int)
    float* dist    = (float*)d_ws;
    float* partial = dist + (size_t)BSZ * BSZ;
    int*   counter = (int*)(partial + BSZ);

    dim3 gd(BSZ / 32, BSZ / 32);
    rll_dist<<<gd, 256, 0, stream>>>(emb, dist, counter);

    rll_count<<<BSZ, 256, 0, stream>>>(dist, labels, partial, counter, out);
}